// Round 9
// baseline (746.265 us; speedup 1.0000x reference)
//
#include <hip/hip_runtime.h>
#include <hip/hip_bf16.h>
#include <hip/hip_cooperative_groups.h>

namespace cg = cooperative_groups;

#define D_FEAT 128
#define D4 (D_FEAT / 4)
#define BKT_SHIFT 7            // 128 nodes per bucket
#define BKT_NODES 128
#define CUR_PAD 16             // one cursor per 64B line
#define BLK 256

// One cooperative kernel, phases separated by grid.sync():
// P0 zero cursors | P1 hist + fp32->bf16 cvt | P2 scan (block 0) |
// P3 XCD-affine partition | P4 per-bucket counting sort | P5 gather+bias.
__global__ __launch_bounds__(BLK, 4) void mega_kernel(
        const int* __restrict__ src, const int* __restrict__ dst,
        const float* __restrict__ vals,
        const float4* __restrict__ feat4, const float* __restrict__ bias,
        float* __restrict__ out,
        __hip_bfloat162* __restrict__ fb16,
        int2* __restrict__ spackA, int2* __restrict__ spackB,
        int* __restrict__ cur, int* __restrict__ offsets,
        int* __restrict__ nodeoff,
        int E, int N, int NBKT, int nseg, int n4) {
    cg::grid_group grid = cg::this_grid();
    const int tid = threadIdx.x;
    const int bid = blockIdx.x;
    const int gsize = gridDim.x * BLK;
    const int gtid = bid * BLK + tid;

    // ---- P0: zero cursors ----
    for (int i = gtid; i < nseg * CUR_PAD; i += gsize) cur[i] = 0;
    grid.sync();

    // ---- P1: histogram (bucket,slot) + bf16 convert ----
    // slot=(e>>8)&7 == (processing block id)&7 under this grid-stride map,
    // so each (bucket,slot) region is written by one XCD in P3.
    for (int e = gtid; e < E; e += gsize) {
        int d = dst[e];
        int slot = (e >> 8) & 7;
        atomicAdd(&cur[(((d >> BKT_SHIFT) << 3) + slot) * CUR_PAD], 1);
    }
    for (int i = gtid; i < n4; i += gsize) {
        float4 f = feat4[i];
        fb16[2 * i + 0] = __float22bfloat162_rn(make_float2(f.x, f.y));
        fb16[2 * i + 1] = __float22bfloat162_rn(make_float2(f.z, f.w));
    }
    grid.sync();

    // ---- P2: block 0 exclusive-scans nseg strided counts ----
    __shared__ int sscan[BLK];
    if (bid == 0) {
        int per = (nseg + BLK - 1) / BLK;
        int base = tid * per;
        int sum = 0;
        for (int i = 0; i < per; i++) {
            int j = base + i;
            if (j < nseg) sum += cur[j * CUR_PAD];
        }
        sscan[tid] = sum;
        __syncthreads();
        for (int off = 1; off < BLK; off <<= 1) {
            int t = (tid >= off) ? sscan[tid - off] : 0;
            __syncthreads();
            sscan[tid] += t;
            __syncthreads();
        }
        int excl = sscan[tid] - sum;
        for (int i = 0; i < per; i++) {
            int j = base + i;
            if (j < nseg) {
                int c = cur[j * CUR_PAD];
                offsets[j] = excl;
                cur[j * CUR_PAD] = excl;
                excl += c;
            }
        }
        if (tid == BLK - 1) offsets[nseg] = sscan[BLK - 1];
    }
    grid.sync();

    // ---- P3: partition edges into (bucket,slot) regions ----
    for (int e = gtid; e < E; e += gsize) {
        int d = dst[e];
        int s = src[e];
        float v = vals[e];
        int slot = (e >> 8) & 7;
        int idx = (((d >> BKT_SHIFT) << 3) + slot) * CUR_PAD;
        int pos = atomicAdd(&cur[idx], 1);
        spackA[pos] = make_int2((s & 0xFFFF) | ((d & (BKT_NODES - 1)) << 16),
                                __float_as_int(v));
    }
    grid.sync();

    // ---- P4: per-bucket counting sort -> spackB, nodeoff ----
    __shared__ int hist[BKT_NODES];
    __shared__ int sbuf[BKT_NODES];
    __shared__ int lcur[BKT_NODES];
    for (int b = bid; b < NBKT; b += gridDim.x) {
        int base = offsets[b << 3];
        int end  = offsets[(b + 1) << 3];
        int cnt = end - base;
        if (tid < BKT_NODES) hist[tid] = 0;
        __syncthreads();
        for (int i = tid; i < cnt; i += BLK)
            atomicAdd(&hist[(spackA[base + i].x >> 16) & (BKT_NODES - 1)], 1);
        __syncthreads();
        if (tid < BKT_NODES) sbuf[tid] = hist[tid];
        __syncthreads();
        for (int off = 1; off < BKT_NODES; off <<= 1) {
            int t = (tid < BKT_NODES && tid >= off) ? sbuf[tid - off] : 0;
            __syncthreads();
            if (tid < BKT_NODES) sbuf[tid] += t;
            __syncthreads();
        }
        if (tid < BKT_NODES) {
            int excl = sbuf[tid] - hist[tid];
            lcur[tid] = excl;
            int node = (b << BKT_SHIFT) + tid;
            if (node <= N) nodeoff[node] = base + excl;
        }
        __syncthreads();
        for (int i = tid; i < cnt; i += BLK) {
            int2 r = spackA[base + i];
            int p = atomicAdd(&lcur[(r.x >> 16) & (BKT_NODES - 1)], 1);
            spackB[base + p] = r;
        }
        __syncthreads();
        if (b == NBKT - 1 && tid == 0) nodeoff[N] = end;
    }
    grid.sync();

    // ---- P5: gather (one wave per node, unroll 8, bf16 feats) ----
    const float2* bias2 = (const float2*)bias;
    float2* out2 = (float2*)out;
    int wave = tid >> 6, lane = tid & 63;
    int nwaves = gridDim.x * (BLK / 64);
    for (int node = bid * (BLK / 64) + wave; node < N; node += nwaves) {
        int beg = nodeoff[node], end = nodeoff[node + 1];
        float2 acc0 = bias2[lane];
        float2 acc1 = make_float2(0.f, 0.f);
        int e = beg;
        for (; e + 8 <= end; e += 8) {
            int2 p[8];
            __hip_bfloat162 h[8];
#pragma unroll
            for (int j = 0; j < 8; j++) p[j] = spackB[e + j];
#pragma unroll
            for (int j = 0; j < 8; j++)
                h[j] = fb16[(size_t)(p[j].x & 0xFFFF) * 64 + lane];
#pragma unroll
            for (int j = 0; j < 8; j++) {
                float v = __int_as_float(p[j].y);
                float2 f = __bfloat1622float2(h[j]);
                if (j & 1) { acc1.x += v * f.x; acc1.y += v * f.y; }
                else       { acc0.x += v * f.x; acc0.y += v * f.y; }
            }
        }
        for (; e < end; e++) {
            int2 p = spackB[e];
            float v = __int_as_float(p.y);
            float2 f = __bfloat1622float2(fb16[(size_t)(p.x & 0xFFFF) * 64 + lane]);
            acc0.x += v * f.x; acc0.y += v * f.y;
        }
        acc0.x += acc1.x; acc0.y += acc1.y;
        out2[(size_t)node * 64 + lane] = acc0;
    }
}

// ---------- fallback atomic path ----------

__global__ void init_bias_kernel(float4* __restrict__ out,
                                 const float4* __restrict__ bias, int n4) {
    int i = blockIdx.x * blockDim.x + threadIdx.x;
    if (i < n4) out[i] = bias[i & (D4 - 1)];
}

__global__ void spmm_edge_kernel(const int* __restrict__ src,
                                 const int* __restrict__ dst,
                                 const float* __restrict__ vals,
                                 const float4* __restrict__ feat,
                                 float* __restrict__ out, int n_edges) {
    int tid = blockIdx.x * blockDim.x + threadIdx.x;
    int e = tid >> 5;
    int lane = tid & 31;
    if (e >= n_edges) return;
    int s = src[e];
    int d = dst[e];
    float v = vals[e];
    float4 f = feat[(size_t)s * D4 + lane];
    float* o = out + (size_t)d * D_FEAT + lane * 4;
    atomicAdd(o + 0, v * f.x);
    atomicAdd(o + 1, v * f.y);
    atomicAdd(o + 2, v * f.z);
    atomicAdd(o + 3, v * f.w);
}

extern "C" void kernel_launch(void* const* d_in, const int* in_sizes, int n_in,
                              void* d_out, int out_size, void* d_ws, size_t ws_size,
                              hipStream_t stream) {
    const int* edge_index = (const int*)d_in[0];    // (2, E) int32
    const float* edge_vals = (const float*)d_in[1]; // (E,)
    const float* features  = (const float*)d_in[2]; // (N, 128)
    const float* bias      = (const float*)d_in[3]; // (128,)

    int E = in_sizes[1];
    int N = in_sizes[2] / D_FEAT;
    const int* src = edge_index;
    const int* dst = edge_index + E;
    float* out = (float*)d_out;

    int NBKT = (N + BKT_NODES - 1) >> BKT_SHIFT;
    int nseg = NBKT * 8;
    int n4 = N * D_FEAT / 4;

    // ws: fb16 | spackA | spackB | cur[nseg*16] | offsets[nseg+1] | nodeoff[N+1]
    size_t fb_bytes = (size_t)N * D_FEAT * 2;
    size_t sp_bytes = (size_t)E * 8;
    size_t needed = fb_bytes + 2 * sp_bytes +
                    ((size_t)nseg * CUR_PAD + (nseg + 1) + (N + 1)) * 4;

    bool ok = (ws_size >= needed) && (N >= 1) && (N <= 65536) && (E >= 1) &&
              (in_sizes[3] == D_FEAT) && (nseg <= 65536);

    int maxB = 0;
    if (ok) {
        hipError_t oe = hipOccupancyMaxActiveBlocksPerMultiprocessor(
            &maxB, mega_kernel, BLK, 0);
        if (oe != hipSuccess || maxB < 1) ok = false;
    }

    if (ok) {
        char* wp = (char*)d_ws;
        __hip_bfloat162* fb16 = (__hip_bfloat162*)wp;  wp += fb_bytes;
        int2* spackA = (int2*)wp;                      wp += sp_bytes;
        int2* spackB = (int2*)wp;                      wp += sp_bytes;
        int* cur     = (int*)wp;                       wp += (size_t)nseg * CUR_PAD * 4;
        int* offsets = (int*)wp;                       wp += (size_t)(nseg + 1) * 4;
        int* nodeoff = (int*)wp;

        long long G_ll = (long long)maxB * 256;       // 256 CUs on MI355X
        if (G_ll > 2048) G_ll = 2048;
        int G = (int)(G_ll & ~7LL);                   // multiple of 8 for XCD slots
        if (G < 8) G = 8;

        const float4* feat4 = (const float4*)features;
        void* args[] = { (void*)&src, (void*)&dst, (void*)&edge_vals,
                         (void*)&feat4, (void*)&bias, (void*)&out,
                         (void*)&fb16, (void*)&spackA, (void*)&spackB,
                         (void*)&cur, (void*)&offsets, (void*)&nodeoff,
                         (void*)&E, (void*)&N, (void*)&NBKT,
                         (void*)&nseg, (void*)&n4 };
        hipError_t le = hipLaunchCooperativeKernel((const void*)mega_kernel,
                                                   dim3(G), dim3(BLK),
                                                   args, 0, stream);
        if (le == hipSuccess) return;
        // fall through to fallback on launch failure
    }

    // fallback: atomic scatter-add
    int no4 = out_size / 4;
    {
        int block = 256, grid = (no4 + block - 1) / block;
        init_bias_kernel<<<grid, block, 0, stream>>>((float4*)out,
                                                     (const float4*)bias, no4);
    }
    {
        int block = 256;
        long long total = (long long)E * 32;
        int grid = (int)((total + block - 1) / block);
        spmm_edge_kernel<<<grid, block, 0, stream>>>(src, dst, edge_vals,
                                                     (const float4*)features,
                                                     out, E);
    }
}

// Round 10
// 178.581 us; speedup vs baseline: 4.1789x; 4.1789x over previous
//
#include <hip/hip_runtime.h>
#include <hip/hip_bf16.h>

#define D_FEAT 128
#define D4 (D_FEAT / 4)
#define BKT_SHIFT 7            // 128 nodes per bucket
#define BKT_NODES 128
#define NCHUNK 64              // edge chunks (counting-sort columns)
#define MAXBKT 512

// ---- K1: per-chunk LDS histogram over buckets -> M[bkt*NCHUNK+chunk];
//      blocks >= NCHUNK convert fp32 features -> bf16 table. No atomics on M.
__global__ __launch_bounds__(256) void k1_hist_cvt(
        const int* __restrict__ dst, int E, int chunk, int nbkt,
        int* __restrict__ M, int Mpad,
        const float4* __restrict__ fin, __hip_bfloat162* __restrict__ fout,
        int n4) {
    int c = blockIdx.x;
    int tid = threadIdx.x;
    if (c < NCHUNK) {
        __shared__ int hist[MAXBKT];
        for (int i = tid; i < nbkt; i += 256) hist[i] = 0;
        __syncthreads();
        int lo = c * chunk;
        int hi = min(lo + chunk, E);
        for (int i = lo + tid; i < hi; i += 256)
            atomicAdd(&hist[dst[i] >> BKT_SHIFT], 1);
        __syncthreads();
        for (int i = tid; i < nbkt; i += 256)
            M[i * NCHUNK + c] = hist[i];
        if (c == 0) {  // zero scan padding
            for (int i = nbkt * NCHUNK + tid; i < Mpad; i += 256) M[i] = 0;
        }
    } else {
        int nb = gridDim.x - NCHUNK;
        int idx = (c - NCHUNK) * 256 + tid;
        int stride = nb * 256;
        for (int i = idx; i < n4; i += stride) {
            float4 f = fin[i];
            fout[2 * i + 0] = __float22bfloat162_rn(make_float2(f.x, f.y));
            fout[2 * i + 1] = __float22bfloat162_rn(make_float2(f.z, f.w));
        }
    }
}

// ---- K2a: block-local exclusive scan of 1024 contiguous M entries (in place),
//      block total -> bsum[blk]. Add-back deferred to consumers.
__global__ __launch_bounds__(1024) void k2a_scan(int* __restrict__ M,
                                                 int* __restrict__ bsum) {
    __shared__ int s[1024];
    int tid = threadIdx.x;
    int j = blockIdx.x * 1024 + tid;
    int v = M[j];
    s[tid] = v;
    __syncthreads();
    for (int off = 1; off < 1024; off <<= 1) {
        int t = (tid >= off) ? s[tid - off] : 0;
        __syncthreads();
        s[tid] += t;
        __syncthreads();
    }
    M[j] = s[tid] - v;
    if (tid == 1023) bsum[blockIdx.x] = s[1023];
}

// ---- K2b: exclusive scan of <=64 block sums; bsum[nb] = total.
__global__ void k2b_scan(int* __restrict__ bsum, int nb) {
    __shared__ int s[64];
    int tid = threadIdx.x;
    int v = (tid < nb) ? bsum[tid] : 0;
    s[tid] = v;
    __syncthreads();
    for (int off = 1; off < 64; off <<= 1) {
        int t = (tid >= off) ? s[tid - off] : 0;
        __syncthreads();
        s[tid] += t;
        __syncthreads();
    }
    if (tid < nb) bsum[tid] = s[tid] - v;
    if (tid == 63) bsum[nb] = s[63];
}

// ---- K3: partition. Block c re-reads its chunk; LDS cursors seeded from the
//      scanned matrix; writes land in ~(chunk/nbkt)-edge contiguous runs.
__global__ __launch_bounds__(256) void k3_partition(
        const int* __restrict__ src, const int* __restrict__ dst,
        const float* __restrict__ vals, int E, int chunk, int nbkt,
        const int* __restrict__ M, const int* __restrict__ bsum,
        int2* __restrict__ spackA) {
    __shared__ int lcur[MAXBKT];
    int c = blockIdx.x;
    int tid = threadIdx.x;
    for (int i = tid; i < nbkt; i += 256) {
        int j = i * NCHUNK + c;
        lcur[i] = M[j] + bsum[j >> 10];
    }
    __syncthreads();
    int lo = c * chunk;
    int hi = min(lo + chunk, E);
    for (int i = lo + tid; i < hi; i += 256) {
        int d = dst[i];
        int s = src[i];
        float v = vals[i];
        int pos = atomicAdd(&lcur[d >> BKT_SHIFT], 1);
        spackA[pos] = make_int2((s & 0xFFFF) | ((d & (BKT_NODES - 1)) << 16),
                                __float_as_int(v));
    }
}

// ---- K4: per-bucket counting sort by local row -> spackB + nodeoff.
__global__ __launch_bounds__(256) void k4_bucket_sort(
        const int* __restrict__ M, const int* __restrict__ bsum,
        const int2* __restrict__ spackA, int2* __restrict__ spackB,
        int* __restrict__ nodeoff, int N, int nbkt) {
    __shared__ int hist[BKT_NODES];
    __shared__ int sbuf[BKT_NODES];
    __shared__ int lcur[BKT_NODES];
    int b = blockIdx.x;
    int tid = threadIdx.x;
    int j0 = b * NCHUNK;
    int j1 = (b + 1) * NCHUNK;
    int base = M[j0] + bsum[j0 >> 10];
    int end  = M[j1] + bsum[j1 >> 10];
    int cnt = end - base;

    if (tid < BKT_NODES) hist[tid] = 0;
    __syncthreads();
    for (int i = tid; i < cnt; i += 256)
        atomicAdd(&hist[(spackA[base + i].x >> 16) & (BKT_NODES - 1)], 1);
    __syncthreads();
    if (tid < BKT_NODES) sbuf[tid] = hist[tid];
    __syncthreads();
    for (int off = 1; off < BKT_NODES; off <<= 1) {
        int t = (tid < BKT_NODES && tid >= off) ? sbuf[tid - off] : 0;
        __syncthreads();
        if (tid < BKT_NODES) sbuf[tid] += t;
        __syncthreads();
    }
    if (tid < BKT_NODES) {
        int excl = sbuf[tid] - hist[tid];
        lcur[tid] = excl;
        int node = (b << BKT_SHIFT) + tid;
        if (node <= N) nodeoff[node] = base + excl;
    }
    __syncthreads();
    for (int i = tid; i < cnt; i += 256) {
        int2 r = spackA[base + i];
        int p = atomicAdd(&lcur[(r.x >> 16) & (BKT_NODES - 1)], 1);
        spackB[base + p] = r;
    }
    if (b == nbkt - 1 && tid == 0) nodeoff[N] = end;
}

// ---- K5: gather, one wave per node, unroll 8, bf16 feats + fp32 acc. ----
__global__ void k5_gather(const int* __restrict__ nodeoff,
                          const int2* __restrict__ spack,
                          const __hip_bfloat162* __restrict__ feat,
                          const float2* __restrict__ bias2,
                          float2* __restrict__ out2, int n_nodes) {
    int gtid = blockIdx.x * blockDim.x + threadIdx.x;
    int node = gtid >> 6;
    int lane = gtid & 63;
    if (node >= n_nodes) return;

    int beg = nodeoff[node];
    int end = nodeoff[node + 1];
    float2 acc0 = bias2[lane];
    float2 acc1 = make_float2(0.f, 0.f);

    int e = beg;
    for (; e + 8 <= end; e += 8) {
        int2 p[8];
        __hip_bfloat162 h[8];
#pragma unroll
        for (int j = 0; j < 8; j++) p[j] = spack[e + j];
#pragma unroll
        for (int j = 0; j < 8; j++)
            h[j] = feat[(size_t)(p[j].x & 0xFFFF) * 64 + lane];
#pragma unroll
        for (int j = 0; j < 8; j++) {
            float v = __int_as_float(p[j].y);
            float2 f = __bfloat1622float2(h[j]);
            if (j & 1) { acc1.x += v * f.x; acc1.y += v * f.y; }
            else       { acc0.x += v * f.x; acc0.y += v * f.y; }
        }
    }
    for (; e < end; e++) {
        int2 p = spack[e];
        float v = __int_as_float(p.y);
        float2 f = __bfloat1622float2(feat[(size_t)(p.x & 0xFFFF) * 64 + lane]);
        acc0.x += v * f.x; acc0.y += v * f.y;
    }
    acc0.x += acc1.x; acc0.y += acc1.y;
    out2[(size_t)node * 64 + lane] = acc0;
}

// ---------- fallback atomic path ----------

__global__ void init_bias_kernel(float4* __restrict__ out,
                                 const float4* __restrict__ bias, int n4) {
    int i = blockIdx.x * blockDim.x + threadIdx.x;
    if (i < n4) out[i] = bias[i & (D4 - 1)];
}

__global__ void spmm_edge_kernel(const int* __restrict__ src,
                                 const int* __restrict__ dst,
                                 const float* __restrict__ vals,
                                 const float4* __restrict__ feat,
                                 float* __restrict__ out, int n_edges) {
    int tid = blockIdx.x * blockDim.x + threadIdx.x;
    int e = tid >> 5;
    int lane = tid & 31;
    if (e >= n_edges) return;
    int s = src[e];
    int d = dst[e];
    float v = vals[e];
    float4 f = feat[(size_t)s * D4 + lane];
    float* o = out + (size_t)d * D_FEAT + lane * 4;
    atomicAdd(o + 0, v * f.x);
    atomicAdd(o + 1, v * f.y);
    atomicAdd(o + 2, v * f.z);
    atomicAdd(o + 3, v * f.w);
}

extern "C" void kernel_launch(void* const* d_in, const int* in_sizes, int n_in,
                              void* d_out, int out_size, void* d_ws, size_t ws_size,
                              hipStream_t stream) {
    const int* edge_index = (const int*)d_in[0];    // (2, E) int32
    const float* edge_vals = (const float*)d_in[1]; // (E,)
    const float* features  = (const float*)d_in[2]; // (N, 128)
    const float* bias      = (const float*)d_in[3]; // (128,)

    int E = in_sizes[1];
    int N = in_sizes[2] / D_FEAT;
    const int* src = edge_index;
    const int* dst = edge_index + E;
    float* out = (float*)d_out;

    int nbkt = (N + BKT_NODES - 1) >> BKT_SHIFT;
    int n4 = N * D_FEAT / 4;
    int chunk = (E + NCHUNK - 1) / NCHUNK;
    int Mpad = ((nbkt * NCHUNK + 1 + 1023) / 1024) * 1024;  // >= nbkt*NCHUNK+1
    int nblk2 = Mpad / 1024;

    // ws: fb16 | spackA | spackB | M[Mpad] | bsum[nblk2+1] | nodeoff[N+1]
    size_t fb_bytes = (size_t)N * D_FEAT * 2;
    size_t sp_bytes = (size_t)E * 8;
    size_t needed = fb_bytes + 2 * sp_bytes +
                    ((size_t)Mpad + (nblk2 + 1) + (N + 1)) * 4;

    bool ok = (ws_size >= needed) && (N >= 1) && (N <= 65536) && (E >= 1) &&
              (in_sizes[3] == D_FEAT) && (nbkt <= MAXBKT) && (nblk2 <= 64);

    if (ok) {
        char* wp = (char*)d_ws;
        __hip_bfloat162* fb16 = (__hip_bfloat162*)wp;  wp += fb_bytes;
        int2* spackA = (int2*)wp;                      wp += sp_bytes;
        int2* spackB = (int2*)wp;                      wp += sp_bytes;
        int* M       = (int*)wp;                       wp += (size_t)Mpad * 4;
        int* bsum    = (int*)wp;                       wp += (size_t)(nblk2 + 1) * 4;
        int* nodeoff = (int*)wp;

        k1_hist_cvt<<<NCHUNK + 192, 256, 0, stream>>>(dst, E, chunk, nbkt,
                                                      M, Mpad,
                                                      (const float4*)features,
                                                      fb16, n4);
        k2a_scan<<<nblk2, 1024, 0, stream>>>(M, bsum);
        k2b_scan<<<1, 64, 0, stream>>>(bsum, nblk2);
        k3_partition<<<NCHUNK, 256, 0, stream>>>(src, dst, edge_vals, E, chunk,
                                                 nbkt, M, bsum, spackA);
        k4_bucket_sort<<<nbkt, 256, 0, stream>>>(M, bsum, spackA, spackB,
                                                 nodeoff, N, nbkt);
        {
            long long total = (long long)N * 64;
            int block = 256;
            int grid = (int)((total + block - 1) / block);
            k5_gather<<<grid, block, 0, stream>>>(nodeoff, spackB, fb16,
                                                  (const float2*)bias,
                                                  (float2*)out, N);
        }
    } else {
        int no4 = out_size / 4;
        {
            int block = 256, grid = (no4 + block - 1) / block;
            init_bias_kernel<<<grid, block, 0, stream>>>((float4*)out,
                                                         (const float4*)bias, no4);
        }
        {
            int block = 256;
            long long total = (long long)E * 32;
            int grid = (int)((total + block - 1) / block);
            spmm_edge_kernel<<<grid, block, 0, stream>>>(src, dst, edge_vals,
                                                         (const float4*)features,
                                                         out, E);
        }
    }
}

// Round 11
// 166.058 us; speedup vs baseline: 4.4940x; 1.0754x over previous
//
#include <hip/hip_runtime.h>
#include <hip/hip_bf16.h>

#define D_FEAT 128
#define D4 (D_FEAT / 4)
#define BKT_SHIFT 7            // 128 nodes per bucket
#define BKT_NODES 128
#define NCHUNK 128             // edge chunks (counting-sort columns)
#define MAXBKT 512

// ---- K1: per-chunk LDS histogram over buckets -> M[bkt*NCHUNK+chunk];
//      blocks >= NCHUNK convert fp32 features -> bf16 table. No atomics on M.
__global__ __launch_bounds__(256) void k1_hist_cvt(
        const int* __restrict__ dst, int E, int chunk, int nbkt,
        int* __restrict__ M, int Mpad,
        const float4* __restrict__ fin, __hip_bfloat162* __restrict__ fout,
        int n4) {
    int c = blockIdx.x;
    int tid = threadIdx.x;
    if (c < NCHUNK) {
        __shared__ int hist[MAXBKT];
        for (int i = tid; i < nbkt; i += 256) hist[i] = 0;
        __syncthreads();
        int lo = c * chunk;
        int hi = min(lo + chunk, E);
        for (int i = lo + tid; i < hi; i += 256)
            atomicAdd(&hist[dst[i] >> BKT_SHIFT], 1);
        __syncthreads();
        for (int i = tid; i < nbkt; i += 256)
            M[i * NCHUNK + c] = hist[i];
        if (c == 0) {  // zero scan padding
            for (int i = nbkt * NCHUNK + tid; i < Mpad; i += 256) M[i] = 0;
        }
    } else {
        int nb = gridDim.x - NCHUNK;
        int idx = (c - NCHUNK) * 256 + tid;
        int stride = nb * 256;
        for (int i = idx; i < n4; i += stride) {
            float4 f = fin[i];
            fout[2 * i + 0] = __float22bfloat162_rn(make_float2(f.x, f.y));
            fout[2 * i + 1] = __float22bfloat162_rn(make_float2(f.z, f.w));
        }
    }
}

// ---- K2a: block-local exclusive scan of 1024 contiguous M entries (in place),
//      block total -> bsum[blk]. Add-back deferred to consumers.
__global__ __launch_bounds__(1024) void k2a_scan(int* __restrict__ M,
                                                 int* __restrict__ bsum) {
    __shared__ int s[1024];
    int tid = threadIdx.x;
    int j = blockIdx.x * 1024 + tid;
    int v = M[j];
    s[tid] = v;
    __syncthreads();
    for (int off = 1; off < 1024; off <<= 1) {
        int t = (tid >= off) ? s[tid - off] : 0;
        __syncthreads();
        s[tid] += t;
        __syncthreads();
    }
    M[j] = s[tid] - v;
    if (tid == 1023) bsum[blockIdx.x] = s[1023];
}

// ---- K2b: exclusive scan of <=64 block sums.
__global__ void k2b_scan(int* __restrict__ bsum, int nb) {
    __shared__ int s[64];
    int tid = threadIdx.x;
    int v = (tid < nb) ? bsum[tid] : 0;
    s[tid] = v;
    __syncthreads();
    for (int off = 1; off < 64; off <<= 1) {
        int t = (tid >= off) ? s[tid - off] : 0;
        __syncthreads();
        s[tid] += t;
        __syncthreads();
    }
    if (tid < nb) bsum[tid] = s[tid] - v;
    if (tid == 63) bsum[nb] = s[63];
}

// ---- K3: partition. Block c re-reads its chunk; LDS cursors seeded from the
//      scanned matrix; writes land in ~(chunk/nbkt)-edge contiguous runs.
__global__ __launch_bounds__(256) void k3_partition(
        const int* __restrict__ src, const int* __restrict__ dst,
        const float* __restrict__ vals, int E, int chunk, int nbkt,
        const int* __restrict__ M, const int* __restrict__ bsum,
        int2* __restrict__ spackA) {
    __shared__ int lcur[MAXBKT];
    int c = blockIdx.x;
    int tid = threadIdx.x;
    for (int i = tid; i < nbkt; i += 256) {
        int j = i * NCHUNK + c;
        lcur[i] = M[j] + bsum[j >> 10];
    }
    __syncthreads();
    int lo = c * chunk;
    int hi = min(lo + chunk, E);
    for (int i = lo + tid; i < hi; i += 256) {
        int d = dst[i];
        int s = src[i];
        float v = vals[i];
        int pos = atomicAdd(&lcur[d >> BKT_SHIFT], 1);
        spackA[pos] = make_int2((s & 0xFFFF) | ((d & (BKT_NODES - 1)) << 16),
                                __float_as_int(v));
    }
}

// ---- K45: merged per-bucket counting sort + gather. Block b sorts its bucket
//      into spackB (stays in this XCD's L2), then its 16 waves gather:
//      wave w handles local nodes w, w+16, ...; lane l = feature pair l.
__global__ __launch_bounds__(1024) void k45_sort_gather(
        const int* __restrict__ M, const int* __restrict__ bsum,
        const int2* __restrict__ spackA, int2* __restrict__ spackB,
        const __hip_bfloat162* __restrict__ feat,
        const float2* __restrict__ bias2, float2* __restrict__ out2,
        int N, int nbkt) {
    __shared__ int hist[BKT_NODES];
    __shared__ int sbuf[BKT_NODES];   // inclusive scan (preserved for gather)
    __shared__ int lcur[BKT_NODES];
    int b = blockIdx.x;
    int tid = threadIdx.x;
    int j0 = b * NCHUNK;
    int j1 = (b + 1) * NCHUNK;
    int base = M[j0] + bsum[j0 >> 10];
    int end  = M[j1] + bsum[j1 >> 10];
    int cnt = end - base;

    if (tid < BKT_NODES) hist[tid] = 0;
    __syncthreads();
    for (int i = tid; i < cnt; i += 1024)
        atomicAdd(&hist[(spackA[base + i].x >> 16) & (BKT_NODES - 1)], 1);
    __syncthreads();
    if (tid < BKT_NODES) sbuf[tid] = hist[tid];
    __syncthreads();
    for (int off = 1; off < BKT_NODES; off <<= 1) {
        int t = (tid < BKT_NODES && tid >= off) ? sbuf[tid - off] : 0;
        __syncthreads();
        if (tid < BKT_NODES) sbuf[tid] += t;
        __syncthreads();
    }
    if (tid < BKT_NODES) lcur[tid] = sbuf[tid] - hist[tid];
    __syncthreads();
    for (int i = tid; i < cnt; i += 1024) {
        int2 r = spackA[base + i];
        int p = atomicAdd(&lcur[(r.x >> 16) & (BKT_NODES - 1)], 1);
        spackB[base + p] = r;
    }
    __syncthreads();   // spackB visible block-wide (same XCD L2)

    int wave = tid >> 6, lane = tid & 63;
    float2 bv = bias2[lane];
    for (int n = wave; n < BKT_NODES; n += 16) {
        int node = (b << BKT_SHIFT) + n;
        if (node >= N) break;
        int beg = base + sbuf[n] - hist[n];
        int eend = base + sbuf[n];
        float2 acc0 = bv;
        float2 acc1 = make_float2(0.f, 0.f);
        int e = beg;
        for (; e + 8 <= eend; e += 8) {
            int2 p[8];
            __hip_bfloat162 h[8];
#pragma unroll
            for (int j = 0; j < 8; j++) p[j] = spackB[e + j];
#pragma unroll
            for (int j = 0; j < 8; j++)
                h[j] = feat[(size_t)(p[j].x & 0xFFFF) * 64 + lane];
#pragma unroll
            for (int j = 0; j < 8; j++) {
                float v = __int_as_float(p[j].y);
                float2 f = __bfloat1622float2(h[j]);
                if (j & 1) { acc1.x += v * f.x; acc1.y += v * f.y; }
                else       { acc0.x += v * f.x; acc0.y += v * f.y; }
            }
        }
        for (; e < eend; e++) {
            int2 p = spackB[e];
            float v = __int_as_float(p.y);
            float2 f = __bfloat1622float2(feat[(size_t)(p.x & 0xFFFF) * 64 + lane]);
            acc0.x += v * f.x; acc0.y += v * f.y;
        }
        acc0.x += acc1.x; acc0.y += acc1.y;
        out2[(size_t)node * 64 + lane] = acc0;
    }
}

// ---------- fallback atomic path ----------

__global__ void init_bias_kernel(float4* __restrict__ out,
                                 const float4* __restrict__ bias, int n4) {
    int i = blockIdx.x * blockDim.x + threadIdx.x;
    if (i < n4) out[i] = bias[i & (D4 - 1)];
}

__global__ void spmm_edge_kernel(const int* __restrict__ src,
                                 const int* __restrict__ dst,
                                 const float* __restrict__ vals,
                                 const float4* __restrict__ feat,
                                 float* __restrict__ out, int n_edges) {
    int tid = blockIdx.x * blockDim.x + threadIdx.x;
    int e = tid >> 5;
    int lane = tid & 31;
    if (e >= n_edges) return;
    int s = src[e];
    int d = dst[e];
    float v = vals[e];
    float4 f = feat[(size_t)s * D4 + lane];
    float* o = out + (size_t)d * D_FEAT + lane * 4;
    atomicAdd(o + 0, v * f.x);
    atomicAdd(o + 1, v * f.y);
    atomicAdd(o + 2, v * f.z);
    atomicAdd(o + 3, v * f.w);
}

extern "C" void kernel_launch(void* const* d_in, const int* in_sizes, int n_in,
                              void* d_out, int out_size, void* d_ws, size_t ws_size,
                              hipStream_t stream) {
    const int* edge_index = (const int*)d_in[0];    // (2, E) int32
    const float* edge_vals = (const float*)d_in[1]; // (E,)
    const float* features  = (const float*)d_in[2]; // (N, 128)
    const float* bias      = (const float*)d_in[3]; // (128,)

    int E = in_sizes[1];
    int N = in_sizes[2] / D_FEAT;
    const int* src = edge_index;
    const int* dst = edge_index + E;
    float* out = (float*)d_out;

    int nbkt = (N + BKT_NODES - 1) >> BKT_SHIFT;
    int n4 = N * D_FEAT / 4;
    int chunk = (E + NCHUNK - 1) / NCHUNK;
    int Mpad = ((nbkt * NCHUNK + 1 + 1023) / 1024) * 1024;  // >= nbkt*NCHUNK+1
    int nblk2 = Mpad / 1024;

    // ws: fb16 | spackA | spackB | M[Mpad] | bsum[nblk2+1]
    size_t fb_bytes = (size_t)N * D_FEAT * 2;
    size_t sp_bytes = (size_t)E * 8;
    size_t needed = fb_bytes + 2 * sp_bytes +
                    ((size_t)Mpad + (nblk2 + 1)) * 4;

    bool ok = (ws_size >= needed) && (N >= 1) && (N <= 65536) && (E >= 1) &&
              (in_sizes[3] == D_FEAT) && (nbkt <= MAXBKT) && (nblk2 <= 64);

    if (ok) {
        char* wp = (char*)d_ws;
        __hip_bfloat162* fb16 = (__hip_bfloat162*)wp;  wp += fb_bytes;
        int2* spackA = (int2*)wp;                      wp += sp_bytes;
        int2* spackB = (int2*)wp;                      wp += sp_bytes;
        int* M       = (int*)wp;                       wp += (size_t)Mpad * 4;
        int* bsum    = (int*)wp;

        k1_hist_cvt<<<NCHUNK + 192, 256, 0, stream>>>(dst, E, chunk, nbkt,
                                                      M, Mpad,
                                                      (const float4*)features,
                                                      fb16, n4);
        k2a_scan<<<nblk2, 1024, 0, stream>>>(M, bsum);
        k2b_scan<<<1, 64, 0, stream>>>(bsum, nblk2);
        k3_partition<<<NCHUNK, 256, 0, stream>>>(src, dst, edge_vals, E, chunk,
                                                 nbkt, M, bsum, spackA);
        k45_sort_gather<<<nbkt, 1024, 0, stream>>>(M, bsum, spackA, spackB,
                                                   fb16, (const float2*)bias,
                                                   (float2*)out, N, nbkt);
    } else {
        int no4 = out_size / 4;
        {
            int block = 256, grid = (no4 + block - 1) / block;
            init_bias_kernel<<<grid, block, 0, stream>>>((float4*)out,
                                                         (const float4*)bias, no4);
        }
        {
            int block = 256;
            long long total = (long long)E * 32;
            int grid = (int)((total + block - 1) / block);
            spmm_edge_kernel<<<grid, block, 0, stream>>>(src, dst, edge_vals,
                                                         (const float4*)features,
                                                         out, E);
        }
    }
}

// Round 12
// 139.518 us; speedup vs baseline: 5.3489x; 1.1902x over previous
//
#include <hip/hip_runtime.h>
#include <hip/hip_bf16.h>

#define D_FEAT 128
#define D4 (D_FEAT / 4)
#define BKT_SHIFT 7            // 128 nodes per bucket
#define BKT_NODES 128
#define NCHUNK 256             // edge chunks (counting-sort columns)
#define MAXBKT 512
#define CAP 3072               // LDS sorted-edge capacity per bucket

// ---- K1: per-chunk LDS histogram over buckets -> M[bkt*NCHUNK+chunk];
//      blocks >= NCHUNK convert fp32 features -> bf16 table.
__global__ __launch_bounds__(256) void k1_hist_cvt(
        const int* __restrict__ dst, int E, int chunk, int nbkt,
        int* __restrict__ M, int Mpad,
        const float4* __restrict__ fin, __hip_bfloat162* __restrict__ fout,
        int n4) {
    int c = blockIdx.x;
    int tid = threadIdx.x;
    if (c < NCHUNK) {
        __shared__ int hist[MAXBKT];
        for (int i = tid; i < nbkt; i += 256) hist[i] = 0;
        __syncthreads();
        int lo = c * chunk;
        int hi = min(lo + chunk, E);
        for (int i = lo + tid; i < hi; i += 256)
            atomicAdd(&hist[dst[i] >> BKT_SHIFT], 1);
        __syncthreads();
        for (int i = tid; i < nbkt; i += 256)
            M[i * NCHUNK + c] = hist[i];
        if (c == 0) {  // zero scan padding
            for (int i = nbkt * NCHUNK + tid; i < Mpad; i += 256) M[i] = 0;
        }
    } else {
        int nb = gridDim.x - NCHUNK;
        int idx = (c - NCHUNK) * 256 + tid;
        int stride = nb * 256;
        for (int i = idx; i < n4; i += stride) {
            float4 f = fin[i];
            fout[2 * i + 0] = __float22bfloat162_rn(make_float2(f.x, f.y));
            fout[2 * i + 1] = __float22bfloat162_rn(make_float2(f.z, f.w));
        }
    }
}

// ---- K2a: block-local exclusive scan of 1024 contiguous M entries (in place),
//      block total -> bsum[blk]. Add-back deferred to consumers.
__global__ __launch_bounds__(1024) void k2a_scan(int* __restrict__ M,
                                                 int* __restrict__ bsum) {
    __shared__ int s[1024];
    int tid = threadIdx.x;
    int j = blockIdx.x * 1024 + tid;
    int v = M[j];
    s[tid] = v;
    __syncthreads();
    for (int off = 1; off < 1024; off <<= 1) {
        int t = (tid >= off) ? s[tid - off] : 0;
        __syncthreads();
        s[tid] += t;
        __syncthreads();
    }
    M[j] = s[tid] - v;
    if (tid == 1023) bsum[blockIdx.x] = s[1023];
}

// ---- K2b: exclusive scan of <=256 block sums.
__global__ void k2b_scan(int* __restrict__ bsum, int nb) {
    __shared__ int s[256];
    int tid = threadIdx.x;
    int v = (tid < nb) ? bsum[tid] : 0;
    s[tid] = v;
    __syncthreads();
    for (int off = 1; off < 256; off <<= 1) {
        int t = (tid >= off) ? s[tid - off] : 0;
        __syncthreads();
        s[tid] += t;
        __syncthreads();
    }
    if (tid < nb) bsum[tid] = s[tid] - v;
    if (tid == 255) bsum[nb] = s[255];
}

// ---- K3: partition. Block c re-reads its chunk; LDS cursors seeded from the
//      scanned matrix; writes land in one-line (~64B) contiguous runs.
__global__ __launch_bounds__(512) void k3_partition(
        const int* __restrict__ src, const int* __restrict__ dst,
        const float* __restrict__ vals, int E, int chunk, int nbkt,
        const int* __restrict__ M, const int* __restrict__ bsum,
        int2* __restrict__ spackA) {
    __shared__ int lcur[MAXBKT];
    int c = blockIdx.x;
    int tid = threadIdx.x;
    for (int i = tid; i < nbkt; i += 512) {
        int j = i * NCHUNK + c;
        lcur[i] = M[j] + bsum[j >> 10];
    }
    __syncthreads();
    int lo = c * chunk;
    int hi = min(lo + chunk, E);
    for (int i = lo + tid; i < hi; i += 512) {
        int d = dst[i];
        int s = src[i];
        float v = vals[i];
        int pos = atomicAdd(&lcur[d >> BKT_SHIFT], 1);
        spackA[pos] = make_int2((s & 0xFFFF) | ((d & (BKT_NODES - 1)) << 16),
                                __float_as_int(v));
    }
}

// ---- K45: per-bucket counting sort INTO LDS + gather from LDS.
//      Overflow (cnt > CAP) falls back to global spackB for that bucket.
__global__ __launch_bounds__(1024) void k45_sort_gather(
        const int* __restrict__ M, const int* __restrict__ bsum,
        const int2* __restrict__ spackA, int2* __restrict__ spackB,
        const __hip_bfloat162* __restrict__ feat,
        const float2* __restrict__ bias2, float2* __restrict__ out2,
        int N, int nbkt) {
    __shared__ int hist[BKT_NODES];
    __shared__ int sbuf[BKT_NODES];   // inclusive scan (kept for gather)
    __shared__ int lcur[BKT_NODES];
    __shared__ int2 ls[CAP];
    int b = blockIdx.x;
    int tid = threadIdx.x;
    int j0 = b * NCHUNK;
    int j1 = (b + 1) * NCHUNK;
    int base = M[j0] + bsum[j0 >> 10];
    int end  = M[j1] + bsum[j1 >> 10];
    int cnt = end - base;
    bool inlds = (cnt <= CAP);

    if (tid < BKT_NODES) hist[tid] = 0;
    __syncthreads();
    for (int i = tid; i < cnt; i += 1024)
        atomicAdd(&hist[(spackA[base + i].x >> 16) & (BKT_NODES - 1)], 1);
    __syncthreads();
    if (tid < BKT_NODES) sbuf[tid] = hist[tid];
    __syncthreads();
    for (int off = 1; off < BKT_NODES; off <<= 1) {
        int t = (tid < BKT_NODES && tid >= off) ? sbuf[tid - off] : 0;
        __syncthreads();
        if (tid < BKT_NODES) sbuf[tid] += t;
        __syncthreads();
    }
    if (tid < BKT_NODES) lcur[tid] = sbuf[tid] - hist[tid];
    __syncthreads();
    for (int i = tid; i < cnt; i += 1024) {
        int2 r = spackA[base + i];
        int p = atomicAdd(&lcur[(r.x >> 16) & (BKT_NODES - 1)], 1);
        if (inlds) ls[p] = r;
        else       spackB[base + p] = r;
    }
    __syncthreads();

    int wave = tid >> 6, lane = tid & 63;
    float2 bv = bias2[lane];
    for (int n = wave; n < BKT_NODES; n += 16) {
        int node = (b << BKT_SHIFT) + n;
        if (node >= N) break;
        int lbeg = sbuf[n] - hist[n];
        int lend = sbuf[n];
        float2 acc0 = bv;
        float2 acc1 = make_float2(0.f, 0.f);
        int e = lbeg;
        if (inlds) {
            for (; e + 8 <= lend; e += 8) {
                int2 p[8];
                __hip_bfloat162 h[8];
#pragma unroll
                for (int j = 0; j < 8; j++) p[j] = ls[e + j];
#pragma unroll
                for (int j = 0; j < 8; j++)
                    h[j] = feat[(size_t)(p[j].x & 0xFFFF) * 64 + lane];
#pragma unroll
                for (int j = 0; j < 8; j++) {
                    float v = __int_as_float(p[j].y);
                    float2 f = __bfloat1622float2(h[j]);
                    if (j & 1) { acc1.x += v * f.x; acc1.y += v * f.y; }
                    else       { acc0.x += v * f.x; acc0.y += v * f.y; }
                }
            }
            for (; e < lend; e++) {
                int2 p = ls[e];
                float v = __int_as_float(p.y);
                float2 f = __bfloat1622float2(feat[(size_t)(p.x & 0xFFFF) * 64 + lane]);
                acc0.x += v * f.x; acc0.y += v * f.y;
            }
        } else {
            for (; e + 8 <= lend; e += 8) {
                int2 p[8];
                __hip_bfloat162 h[8];
#pragma unroll
                for (int j = 0; j < 8; j++) p[j] = spackB[base + e + j];
#pragma unroll
                for (int j = 0; j < 8; j++)
                    h[j] = feat[(size_t)(p[j].x & 0xFFFF) * 64 + lane];
#pragma unroll
                for (int j = 0; j < 8; j++) {
                    float v = __int_as_float(p[j].y);
                    float2 f = __bfloat1622float2(h[j]);
                    if (j & 1) { acc1.x += v * f.x; acc1.y += v * f.y; }
                    else       { acc0.x += v * f.x; acc0.y += v * f.y; }
                }
            }
            for (; e < lend; e++) {
                int2 p = spackB[base + e];
                float v = __int_as_float(p.y);
                float2 f = __bfloat1622float2(feat[(size_t)(p.x & 0xFFFF) * 64 + lane]);
                acc0.x += v * f.x; acc0.y += v * f.y;
            }
        }
        acc0.x += acc1.x; acc0.y += acc1.y;
        out2[(size_t)node * 64 + lane] = acc0;
    }
}

// ---------- fallback atomic path ----------

__global__ void init_bias_kernel(float4* __restrict__ out,
                                 const float4* __restrict__ bias, int n4) {
    int i = blockIdx.x * blockDim.x + threadIdx.x;
    if (i < n4) out[i] = bias[i & (D4 - 1)];
}

__global__ void spmm_edge_kernel(const int* __restrict__ src,
                                 const int* __restrict__ dst,
                                 const float* __restrict__ vals,
                                 const float4* __restrict__ feat,
                                 float* __restrict__ out, int n_edges) {
    int tid = blockIdx.x * blockDim.x + threadIdx.x;
    int e = tid >> 5;
    int lane = tid & 31;
    if (e >= n_edges) return;
    int s = src[e];
    int d = dst[e];
    float v = vals[e];
    float4 f = feat[(size_t)s * D4 + lane];
    float* o = out + (size_t)d * D_FEAT + lane * 4;
    atomicAdd(o + 0, v * f.x);
    atomicAdd(o + 1, v * f.y);
    atomicAdd(o + 2, v * f.z);
    atomicAdd(o + 3, v * f.w);
}

extern "C" void kernel_launch(void* const* d_in, const int* in_sizes, int n_in,
                              void* d_out, int out_size, void* d_ws, size_t ws_size,
                              hipStream_t stream) {
    const int* edge_index = (const int*)d_in[0];    // (2, E) int32
    const float* edge_vals = (const float*)d_in[1]; // (E,)
    const float* features  = (const float*)d_in[2]; // (N, 128)
    const float* bias      = (const float*)d_in[3]; // (128,)

    int E = in_sizes[1];
    int N = in_sizes[2] / D_FEAT;
    const int* src = edge_index;
    const int* dst = edge_index + E;
    float* out = (float*)d_out;

    int nbkt = (N + BKT_NODES - 1) >> BKT_SHIFT;
    int n4 = N * D_FEAT / 4;
    int chunk = (E + NCHUNK - 1) / NCHUNK;
    int Mpad = ((nbkt * NCHUNK + 1 + 1023) / 1024) * 1024;  // >= nbkt*NCHUNK+1
    int nblk2 = Mpad / 1024;

    // ws: fb16 | spackA | spackB | M[Mpad] | bsum[nblk2+1]
    size_t fb_bytes = (size_t)N * D_FEAT * 2;
    size_t sp_bytes = (size_t)E * 8;
    size_t needed = fb_bytes + 2 * sp_bytes +
                    ((size_t)Mpad + (nblk2 + 1)) * 4;

    bool ok = (ws_size >= needed) && (N >= 1) && (N <= 65536) && (E >= 1) &&
              (in_sizes[3] == D_FEAT) && (nbkt <= MAXBKT) && (nblk2 <= 256);

    if (ok) {
        char* wp = (char*)d_ws;
        __hip_bfloat162* fb16 = (__hip_bfloat162*)wp;  wp += fb_bytes;
        int2* spackA = (int2*)wp;                      wp += sp_bytes;
        int2* spackB = (int2*)wp;                      wp += sp_bytes;
        int* M       = (int*)wp;                       wp += (size_t)Mpad * 4;
        int* bsum    = (int*)wp;

        k1_hist_cvt<<<NCHUNK + 256, 256, 0, stream>>>(dst, E, chunk, nbkt,
                                                      M, Mpad,
                                                      (const float4*)features,
                                                      fb16, n4);
        k2a_scan<<<nblk2, 1024, 0, stream>>>(M, bsum);
        k2b_scan<<<1, 256, 0, stream>>>(bsum, nblk2);
        k3_partition<<<NCHUNK, 512, 0, stream>>>(src, dst, edge_vals, E, chunk,
                                                 nbkt, M, bsum, spackA);
        k45_sort_gather<<<nbkt, 1024, 0, stream>>>(M, bsum, spackA, spackB,
                                                   fb16, (const float2*)bias,
                                                   (float2*)out, N, nbkt);
    } else {
        int no4 = out_size / 4;
        {
            int block = 256, grid = (no4 + block - 1) / block;
            init_bias_kernel<<<grid, block, 0, stream>>>((float4*)out,
                                                         (const float4*)bias, no4);
        }
        {
            int block = 256;
            long long total = (long long)E * 32;
            int grid = (int)((total + block - 1) / block);
            spmm_edge_kernel<<<grid, block, 0, stream>>>(src, dst, edge_vals,
                                                         (const float4*)features,
                                                         out, E);
        }
    }
}